// Round 2
// baseline (209.323 us; speedup 1.0000x reference)
//
#include <hip/hip_runtime.h>
#include <math.h>

// Problem constants (from reference): B=128, N=2048, M=128
#define BB 128
#define NN 2048
#define MM 128
#define ROWS 64                       // n-rows per pass_a block
#define CHUNKS (NN / ROWS)            // 32 blocks per batch row
#define OFFSET_EPS 1e-6f
#define COS_EPS 1e-8f

// ---------------------------------------------------------------------------
// Pass A (R2: direct-register reduce, NO LDS tile). One coalesced streaming
// read of memory[B,N,M]; all reductions in registers + shfl:
//   lane layout: 8 lanes/row (h = l&7 covers cols h*4 + j*32, j=0..3),
//   rr = l>>3 row-in-group; wave w covers rows w*16 + i*8 + rr, i=0..1.
//   k' staged in 4 float4 REGISTERS per lane (no ks[] LDS, no tile LDS,
//   no staging barrier). Per-row dot/sq/rowsum combined via shfl_xor 1,2,4.
//   colsum register partials combined via shfl_xor 8,16,32 (rows) then a
//   2 KB s_col cross-wave combine.
// eps folding: dot = Sum v*k' + eps*Sum k'; nm^2 = Sum v^2 + 2 eps Sum v
//              + M eps^2.  exp without max-subtraction (scores in [-1,1]).
// Emits per chunk: ex_buf[b,n], colsum_part[c,b,m], esum_part[c,b],
//                  psum_part[c,b] (= chunk sum of w_prev^gamma).
// LDS total ~2.2 KB -> occupancy bounded only by VGPRs (~8 blocks/CU).
// NO device-scope fences (R4 fan-in fence cost ~470us — never again).
// ---------------------------------------------------------------------------
__global__ __launch_bounds__(256, 4) void pass_a(
    const float* __restrict__ memory, const float* __restrict__ k_t,
    const float* __restrict__ beta_t, const float* __restrict__ w_prev,
    const float* __restrict__ gamma_t,
    float* __restrict__ colsum_part, float* __restrict__ ex_buf,
    float* __restrict__ esum_part,   float* __restrict__ psum_part)
{
    __shared__ float s_col[4][MM];          // per-wave colsum partials
    __shared__ float s_red[4];              // per-wave esum
    __shared__ float s_bon;                 // beta / nk
    __shared__ float s_epsK1;               // eps * Sum(k+eps)

    const int b     = blockIdx.x / CHUNKS;
    const int chunk = blockIdx.x % CHUNKS;
    const int r0    = chunk * ROWS;
    const int t     = threadIdx.x;
    const int w     = t >> 6;               // wave 0..3
    const int l     = t & 63;               // lane 0..63
    const int h     = l & 7;                // column octet 0..7
    const int rr    = l >> 3;               // row within 8-row group

    // ---- per-b constants (wave-0 lanes 0..31) ----
    if (t < 32) {
        float4 kv = *(const float4*)(k_t + b * MM + 4 * t);
        const float e0 = kv.x + OFFSET_EPS, e1 = kv.y + OFFSET_EPS,
                    e2 = kv.z + OFFSET_EPS, e3 = kv.w + OFFSET_EPS;
        float s2 = e0 * e0 + e1 * e1 + e2 * e2 + e3 * e3;
        float s1 = e0 + e1 + e2 + e3;
        #pragma unroll
        for (int s = 16; s; s >>= 1) {
            s2 += __shfl_xor(s2, s);
            s1 += __shfl_xor(s1, s);
        }
        if (t == 0) {
            s_bon   = beta_t[b] / fmaxf(sqrtf(s2), COS_EPS);
            s_epsK1 = OFFSET_EPS * s1;
        }
    }

    // ---- psum partial: w_prev^gamma over this chunk's 64 rows (t<16) ----
    if (t < 16) {
        float4 wv = *(const float4*)(w_prev + b * NN + r0 + 4 * t);
        const float gamma = gamma_t[b];
        float p = __powf(wv.x, gamma) + __powf(wv.y, gamma) +
                  __powf(wv.z, gamma) + __powf(wv.w, gamma);   // w in [0,1)
        #pragma unroll
        for (int s = 8; s; s >>= 1) p += __shfl_xor(p, s);
        if (t == 0) psum_part[chunk * BB + b] = p;
    }

    // ---- k' register fragments: this lane's 16 columns ----
    float4 k4[4];
    #pragma unroll
    for (int j = 0; j < 4; ++j) {
        float4 kv = *(const float4*)(k_t + b * MM + j * 32 + h * 4);
        k4[j] = make_float4(kv.x + OFFSET_EPS, kv.y + OFFSET_EPS,
                            kv.z + OFFSET_EPS, kv.w + OFFSET_EPS);
    }

    // ---- main streaming loop: direct register reduce ----
    const float* src = memory + ((size_t)b * NN + r0 + w * 16) * MM;
    float4 cs[4];
    #pragma unroll
    for (int j = 0; j < 4; ++j) cs[j] = make_float4(0.f, 0.f, 0.f, 0.f);
    float d_[2], q_[2], r_[2];

    #pragma unroll
    for (int i = 0; i < 2; ++i) {
        const float* p = src + (i * 8 + rr) * MM + h * 4;
        float dot = 0.f, sq = 0.f, rs = 0.f;
        #pragma unroll
        for (int j = 0; j < 4; ++j) {
            float4 v = *(const float4*)(p + j * 32);
            dot += v.x * k4[j].x + v.y * k4[j].y +
                   v.z * k4[j].z + v.w * k4[j].w;
            sq  += v.x * v.x + v.y * v.y + v.z * v.z + v.w * v.w;
            rs  += v.x + v.y + v.z + v.w;
            cs[j].x += v.x; cs[j].y += v.y; cs[j].z += v.z; cs[j].w += v.w;
        }
        // combine the 8 lanes of this row (bits 0..2 of lane id)
        dot += __shfl_xor(dot, 1); dot += __shfl_xor(dot, 2); dot += __shfl_xor(dot, 4);
        sq  += __shfl_xor(sq, 1);  sq  += __shfl_xor(sq, 2);  sq  += __shfl_xor(sq, 4);
        rs  += __shfl_xor(rs, 1);  rs  += __shfl_xor(rs, 2);  rs  += __shfl_xor(rs, 4);
        d_[i] = dot; q_[i] = sq; r_[i] = rs;
    }

    // ---- colsum: combine across rows (bits 3..5 of lane id) ----
    #pragma unroll
    for (int j = 0; j < 4; ++j) {
        #pragma unroll
        for (int s = 8; s < 64; s <<= 1) {
            cs[j].x += __shfl_xor(cs[j].x, s);
            cs[j].y += __shfl_xor(cs[j].y, s);
            cs[j].z += __shfl_xor(cs[j].z, s);
            cs[j].w += __shfl_xor(cs[j].w, s);
        }
    }
    if (l < 8) {
        #pragma unroll
        for (int j = 0; j < 4; ++j)
            *(float4*)&s_col[w][l * 4 + j * 32] = cs[j];
    }
    __syncthreads();   // orders s_col writes AND s_bon/s_epsK1 visibility

    // ---- scores -> ex (h==0 lane of each row octet) ----
    float exs = 0.f;
    if (h == 0) {
        const float bon   = s_bon;
        const float epsK1 = s_epsK1;
        #pragma unroll
        for (int i = 0; i < 2; ++i) {
            const float d   = d_[i] + epsK1;
            const float nm2 = q_[i] + 2.0f * OFFSET_EPS * r_[i]
                              + (float)MM * OFFSET_EPS * OFFSET_EPS;
            const float sc  = d * bon / fmaxf(sqrtf(nm2), COS_EPS);
            const float ex  = __expf(sc);
            ex_buf[b * NN + r0 + w * 16 + i * 8 + rr] = ex;
            exs += ex;
        }
    }
    #pragma unroll
    for (int s = 32; s; s >>= 1) exs += __shfl_xor(exs, s);
    if (l == 0) s_red[w] = exs;
    __syncthreads();

    if (t == 0)
        esum_part[chunk * BB + b] = s_red[0] + s_red[1] + s_red[2] + s_red[3];

    // ---- colsum cross-wave combine (threads 0..127, one column each) ----
    if (t < MM) {
        const float v = s_col[0][t] + s_col[1][t] + s_col[2][t] + s_col[3][t];
        colsum_part[(size_t)chunk * (BB * MM) + b * MM + t] = v;
    }
}

// ---------------------------------------------------------------------------
// Pass B: pure streaming epilogue. Grid = 2 blocks per b (256 blocks total),
// each block covers 1024 n's with one float4 sweep. Partial combine is
// lane-parallel (32 lanes load one chunk each + butterfly).
// out[b, 0:M)      = r_t = S*((1-S*e)*colsum + N*S*a)
// out[b, M:M+N)    = w_t = S (broadcast)
// out[b, M+N:M+2N) = w_g = g*ex/esum + (1-g)*w_prev
// ---------------------------------------------------------------------------
__global__ __launch_bounds__(256) void pass_b(
    const float* __restrict__ ex_buf, const float* __restrict__ g_t,
    const float* __restrict__ w_prev, const float* __restrict__ e_t,
    const float* __restrict__ a_t,    const float* __restrict__ colsum_part,
    const float* __restrict__ esum_part, const float* __restrict__ psum_part,
    float* __restrict__ out)
{
    const int b    = blockIdx.x >> 1;
    const int half = blockIdx.x & 1;
    const int t    = threadIdx.x;
    __shared__ float s_inv, s_S;

    if (t < CHUNKS) {   // 32 lanes, one chunk each, butterfly combine
        float es = esum_part[t * BB + b];
        float ps = psum_part[t * BB + b];
        #pragma unroll
        for (int s = 16; s; s >>= 1) {
            es += __shfl_xor(es, s);
            ps += __shfl_xor(ps, s);
        }
        if (t == 0) {
            s_inv = 1.f / es;
            s_S   = ps + OFFSET_EPS;
        }
    }
    __syncthreads();
    const float inv = s_inv, S = s_S, g = g_t[b];

    float* orow = out + (size_t)b * (MM + 2 * NN);
    const int n0 = half * 1024 + 4 * t;
    float4 ex4 = *(const float4*)(ex_buf + b * NN + n0);
    float4 w4  = *(const float4*)(w_prev + b * NN + n0);
    float4 wg;
    wg.x = g * ex4.x * inv + (1.f - g) * w4.x;
    wg.y = g * ex4.y * inv + (1.f - g) * w4.y;
    wg.z = g * ex4.z * inv + (1.f - g) * w4.z;
    wg.w = g * ex4.w * inv + (1.f - g) * w4.w;
    *(float4*)(orow + MM + n0)      = make_float4(S, S, S, S);  // w_t
    *(float4*)(orow + MM + NN + n0) = wg;                       // w_g

    if (half == 0 && t < MM) {
        float cs = 0.f;
        #pragma unroll
        for (int c = 0; c < CHUNKS; ++c)
            cs += colsum_part[(size_t)c * (BB * MM) + b * MM + t];
        orow[t] = S * ((1.f - S * e_t[b * MM + t]) * cs +
                       (float)NN * S * a_t[b * MM + t]);
    }
}

extern "C" void kernel_launch(void* const* d_in, const int* in_sizes, int n_in,
                              void* d_out, int out_size, void* d_ws, size_t ws_size,
                              hipStream_t stream) {
    const float* memory  = (const float*)d_in[0];
    const float* k_t     = (const float*)d_in[1];
    const float* beta_t  = (const float*)d_in[2];
    const float* g_t     = (const float*)d_in[3];
    const float* w_prev  = (const float*)d_in[4];
    // d_in[5] = s_t (unused by the live output chains)
    const float* gamma_t = (const float*)d_in[6];
    const float* e_t     = (const float*)d_in[7];
    const float* a_t     = (const float*)d_in[8];
    float* out = (float*)d_out;

    // ws layout: [colsum_part CHUNKS*B*M | ex B*N | esum CHUNKS*B | psum ...]
    float* colsum_part = (float*)d_ws;
    float* ex_buf      = colsum_part + (size_t)CHUNKS * BB * MM;
    float* esum_part   = ex_buf + BB * NN;
    float* psum_part   = esum_part + CHUNKS * BB;

    pass_a<<<BB * CHUNKS, 256, 0, stream>>>(memory, k_t, beta_t, w_prev,
                                            gamma_t, colsum_part, ex_buf,
                                            esum_part, psum_part);
    pass_b<<<2 * BB, 256, 0, stream>>>(ex_buf, g_t, w_prev, e_t, a_t,
                                       colsum_part, esum_part, psum_part, out);
}